// Round 1
// baseline (67.669 us; speedup 1.0000x reference)
//
#include <hip/hip_runtime.h>

#define BROWS 524288
#define KBINS 64
#define GRID1 2048

// Wave layout: 4 rows per wave, 16 lanes per row, each lane covers 4 bins
// (float4 load). Count stores use a bin = j*16 + l16 mapping so scalar
// stores form 64B-contiguous chunks (d_out+1 is only 4B aligned -> no float4).
__global__ __launch_bounds__(256) void surv_main(
    const float* __restrict__ inp, const float* __restrict__ yv,
    const int* __restrict__ ev, float* __restrict__ out,
    float* __restrict__ block_sums)
{
  const int tid  = threadIdx.x;
  const int lane = tid & 63;
  const int wave = tid >> 6;   // 0..3
  const int sub  = lane >> 4;  // row within wave: 0..3
  const int l16  = lane & 15;  // lane within row-group

  const float S0     = 0.018315638888734179f;  // exp(-4)
  const float INV_S0 = 54.598150033144236f;    // exp(+4)

  float* cnt_out = out + 1;  // count starts after scalar loss
  float acc = 0.0f;

  for (int base = blockIdx.x * 16; base < BROWS; base += gridDim.x * 16) {
    const int row = base + wave * 4 + sub;
    const float y = yv[row];
    const int   e = ev[row];
    const int   b = (int)floorf(y);
    const bool valid    = (y >= 0.0f) && (b < KBINS);
    const bool all_ones = valid && (e == 0) && (b == 0);  // count all 1 -> min==1

    const float4 x = *reinterpret_cast<const float4*>(
        inp + (size_t)row * KBINS + l16 * 4);

    float correct = 0.f, fev = 0.f, fcs = 0.f;
    #pragma unroll
    for (int j = 0; j < 4; ++j) {
      const int bin = l16 * 4 + j;
      const float xj = (j == 0) ? x.x : (j == 1) ? x.y : (j == 2) ? x.z : x.w;
      float c = 0.f;
      if (valid) c = (e != 0) ? (bin == b ? 1.f : 0.f) : (bin >= b ? 1.f : 0.f);
      // margin where count==min(count): c==0 normally, everywhere if all-ones
      const float marg  = (c == 0.f || all_ones) ? 0.1f : 0.0f;
      const float logit = (xj + marg) * 2.0f;
      const float pe  = __expf(-logit);
      const float pen = __expf(logit);
      correct += pe * c;
      fev     += pen * (1.f - c);
      fcs     += pe  * (1.f - c);
    }

    // count stores: bin = j*16 + l16 -> each instruction writes 4x64B chunks
    {
      float* crow = cnt_out + (size_t)row * KBINS;
      #pragma unroll
      for (int j = 0; j < 4; ++j) {
        const int bin = j * 16 + l16;
        float c = 0.f;
        if (valid) c = (e != 0) ? (bin == b ? 1.f : 0.f) : (bin >= b ? 1.f : 0.f);
        crow[bin] = c;
      }
    }

    // reduce the 3 sums over the 16-lane row group
    #pragma unroll
    for (int m = 1; m < 16; m <<= 1) {
      correct += __shfl_xor(correct, m, 64);
      fev     += __shfl_xor(fev, m, 64);
      fcs     += __shfl_xor(fcs, m, 64);
    }

    // sum(count)==1  <=>  valid && (event || b==K-1)
    const bool  is_event = valid && (e != 0 || b == KBINS - 1);
    const float loss_ev  = __logf(correct + S0) + __logf(fev + S0);
    const float loss_cs  = __logf(1.0f + correct * fcs + fcs * INV_S0);
    if (l16 == 0) acc += (is_event ? loss_ev : loss_cs);
  }

  // block reduction of acc (nonzero only at l16==0 lanes)
  acc += __shfl_xor(acc, 16, 64);
  acc += __shfl_xor(acc, 32, 64);
  __shared__ float sm[4];
  if (lane == 0) sm[wave] = acc;
  __syncthreads();
  if (tid == 0) block_sums[blockIdx.x] = (sm[0] + sm[1]) + (sm[2] + sm[3]);
}

__global__ __launch_bounds__(256) void surv_reduce(
    const float* __restrict__ block_sums, float* __restrict__ out)
{
  __shared__ float sm[256];
  float s = 0.f;
  for (int i = threadIdx.x; i < GRID1; i += 256) s += block_sums[i];
  sm[threadIdx.x] = s;
  __syncthreads();
  for (int o = 128; o > 0; o >>= 1) {
    if (threadIdx.x < o) sm[threadIdx.x] += sm[threadIdx.x + o];
    __syncthreads();
  }
  if (threadIdx.x == 0) out[0] = sm[0] * (1.0f / (float)BROWS);
}

extern "C" void kernel_launch(void* const* d_in, const int* in_sizes, int n_in,
                              void* d_out, int out_size, void* d_ws, size_t ws_size,
                              hipStream_t stream) {
  const float* inp = (const float*)d_in[0];
  const float* y   = (const float*)d_in[1];
  const int*   e   = (const int*)d_in[2];
  float* out = (float*)d_out;
  float* block_sums = (float*)d_ws;

  surv_main<<<GRID1, 256, 0, stream>>>(inp, y, e, out, block_sums);
  surv_reduce<<<1, 256, 0, stream>>>(block_sums, out);
}